// Round 2
// baseline (168.923 us; speedup 1.0000x reference)
//
#include <hip/hip_runtime.h>

// Problem constants (fixed by reference setup_inputs)
#define B_      64
#define K_      4
#define M_      3
#define NPIX    65536      // X*Y = 256*256
#define CHUNKS  16         // blocks per image
#define TPB     256        // threads per block
#define ITERS   4          // float4 iterations per thread (16 pixels/thread)
#define NV      16         // 4 den + 12 num partials per thread

// Block (c, b) handles pixels [c*4096, (c+1)*4096) of image b.
// Each thread: 4 x (1 int4 heart + 3 float4 inp + 4 float4 pred) = 512 B.
__global__ __launch_bounds__(TPB, 4) void partial_kernel(
    const float* __restrict__ pred,    // [B,K,NPIX]
    const float* __restrict__ inp,     // [B,M,NPIX]
    const int*   __restrict__ heart,   // [B,NPIX]
    float* __restrict__ partial_ws)    // [B,CHUNKS,NV]
{
    const int c = blockIdx.x;          // chunk 0..15
    const int b = blockIdx.y;          // image 0..63
    const int base = c * (NPIX / CHUNKS) + (int)threadIdx.x * 4;

    float val[NV];
#pragma unroll
    for (int i = 0; i < NV; ++i) val[i] = 0.0f;

#pragma unroll
    for (int it = 0; it < ITERS; ++it) {
        const int pix = base + it * (TPB * 4);

        const int4 h = *reinterpret_cast<const int4*>(heart + (size_t)b * NPIX + pix);
        float4 mask;
        mask.x = (h.x == 1) ? 1.0f : 0.0f;
        mask.y = (h.y == 1) ? 1.0f : 0.0f;
        mask.z = (h.z == 1) ? 1.0f : 0.0f;
        mask.w = (h.w == 1) ? 1.0f : 0.0f;

        float4 in[M_];
#pragma unroll
        for (int m = 0; m < M_; ++m)
            in[m] = *reinterpret_cast<const float4*>(inp + ((size_t)b * M_ + m) * NPIX + pix);

#pragma unroll
        for (int k = 0; k < K_; ++k) {
            float4 p = *reinterpret_cast<const float4*>(pred + ((size_t)b * K_ + k) * NPIX + pix);
            float4 pm;
            pm.x = p.x * mask.x; pm.y = p.y * mask.y;
            pm.z = p.z * mask.z; pm.w = p.w * mask.w;
            val[k] += (pm.x + pm.y) + (pm.z + pm.w);
#pragma unroll
            for (int m = 0; m < M_; ++m)
                val[4 + k * M_ + m] += pm.x * in[m].x + pm.y * in[m].y
                                     + pm.z * in[m].z + pm.w * in[m].w;
        }
    }

    // wave64 shuffle reduction (result lands on lane 0 of each wave)
#pragma unroll
    for (int off = 32; off > 0; off >>= 1) {
#pragma unroll
        for (int i = 0; i < NV; ++i)
            val[i] += __shfl_down(val[i], off, 64);
    }

    __shared__ float smem[TPB / 64][NV];
    const int lane = threadIdx.x & 63;
    const int wave = threadIdx.x >> 6;
    if (lane == 0) {
#pragma unroll
        for (int i = 0; i < NV; ++i) smem[wave][i] = val[i];
    }
    __syncthreads();

    if (threadIdx.x < NV) {
        const float s = smem[0][threadIdx.x] + smem[1][threadIdx.x]
                      + smem[2][threadIdx.x] + smem[3][threadIdx.x];
        partial_ws[((size_t)b * CHUNKS + c) * NV + threadIdx.x] = s;
    }
}

// One wave: lane b owns image b; sum its 16 chunk-partials, form ratios,
// reduce the 12 ratios over b, write the scalar.
__global__ __launch_bounds__(64) void finalize_kernel(
    const float* __restrict__ partial_ws,  // [B,CHUNKS,NV]
    const float* __restrict__ mu_data,     // [K,M]
    float* __restrict__ out)               // [1]
{
    const int b = threadIdx.x;  // 0..63 == B_
    float acc[NV];
#pragma unroll
    for (int i = 0; i < NV; ++i) acc[i] = 0.0f;
    for (int c = 0; c < CHUNKS; ++c) {
        const float* p = partial_ws + ((size_t)b * CHUNKS + c) * NV;
#pragma unroll
        for (int i = 0; i < NV; ++i) acc[i] += p[i];
    }

    float r[K_ * M_];
#pragma unroll
    for (int k = 0; k < K_; ++k) {
        const float inv = 1.0f / (acc[k] + 1e-10f);
#pragma unroll
        for (int m = 0; m < M_; ++m)
            r[k * M_ + m] = acc[4 + k * M_ + m] * inv;
    }
#pragma unroll
    for (int off = 32; off > 0; off >>= 1) {
#pragma unroll
        for (int i = 0; i < K_ * M_; ++i)
            r[i] += __shfl_down(r[i], off, 64);
    }
    if (b == 0) {
        float s = 0.0f;
#pragma unroll
        for (int i = 0; i < K_ * M_; ++i) {
            const float d = mu_data[i] - r[i] * (1.0f / (float)B_);
            s += d * d;
        }
        out[0] = s;
    }
}

extern "C" void kernel_launch(void* const* d_in, const int* in_sizes, int n_in,
                              void* d_out, int out_size, void* d_ws, size_t ws_size,
                              hipStream_t stream) {
    const float* pred    = (const float*)d_in[0];  // [64,4,256,256] f32
    const float* inp     = (const float*)d_in[1];  // [64,3,256,256] f32
    const int*   heart   = (const int*)d_in[2];    // [64,1,256,256] i32
    const float* mu_data = (const float*)d_in[3];  // [4,3] f32
    float* out = (float*)d_out;

    float* partial_ws = (float*)d_ws;  // [B][CHUNKS][NV] — fully written each call

    dim3 grid(CHUNKS, B_);
    partial_kernel<<<grid, TPB, 0, stream>>>(pred, inp, heart, partial_ws);
    finalize_kernel<<<1, 64, 0, stream>>>(partial_ws, mu_data, out);
}

// Round 3
// 155.419 us; speedup vs baseline: 1.0869x; 1.0869x over previous
//
#include <hip/hip_runtime.h>

// Problem constants (fixed by reference setup_inputs)
#define B_      64
#define K_      4
#define M_      3
#define NPIX    65536      // X*Y = 256*256
#define CHUNKS  32         // blocks per image
#define TPB     256        // threads per block
#define ITERS   2          // float4 sub-iterations per thread (8 consecutive px)
#define NV      16         // 4 den + 12 num partials per thread

// Block (c, b) handles pixels [c*2048, (c+1)*2048) of image b.
// Each thread owns 8 CONSECUTIVE pixels: 2 int4 heart + 6 float4 inp +
// 8 float4 pred = 16 independent loads, 256 B in flight per thread.
// NOTE: no min-waves __launch_bounds__ — R2 showed capping VGPRs at 64
// spills the unrolled loads to scratch (+26 MB WRITE_SIZE, +16 us).
__global__ __launch_bounds__(TPB) void partial_kernel(
    const float* __restrict__ pred,    // [B,K,NPIX]
    const float* __restrict__ inp,     // [B,M,NPIX]
    const int*   __restrict__ heart,   // [B,NPIX]
    float* __restrict__ partial_ws)    // [B,CHUNKS,NV]
{
    const int c = blockIdx.x;          // chunk 0..CHUNKS-1
    const int b = blockIdx.y;          // image 0..63
    const int base = c * (NPIX / CHUNKS) + (int)threadIdx.x * (4 * ITERS);

    float val[NV];
#pragma unroll
    for (int i = 0; i < NV; ++i) val[i] = 0.0f;

#pragma unroll
    for (int it = 0; it < ITERS; ++it) {
        const int pix = base + it * 4;   // consecutive pixels per thread

        const int4 h = *reinterpret_cast<const int4*>(heart + (size_t)b * NPIX + pix);
        float4 mask;
        mask.x = (h.x == 1) ? 1.0f : 0.0f;
        mask.y = (h.y == 1) ? 1.0f : 0.0f;
        mask.z = (h.z == 1) ? 1.0f : 0.0f;
        mask.w = (h.w == 1) ? 1.0f : 0.0f;

        float4 in[M_];
#pragma unroll
        for (int m = 0; m < M_; ++m)
            in[m] = *reinterpret_cast<const float4*>(inp + ((size_t)b * M_ + m) * NPIX + pix);

#pragma unroll
        for (int k = 0; k < K_; ++k) {
            float4 p = *reinterpret_cast<const float4*>(pred + ((size_t)b * K_ + k) * NPIX + pix);
            float4 pm;
            pm.x = p.x * mask.x; pm.y = p.y * mask.y;
            pm.z = p.z * mask.z; pm.w = p.w * mask.w;
            val[k] += (pm.x + pm.y) + (pm.z + pm.w);
#pragma unroll
            for (int m = 0; m < M_; ++m)
                val[4 + k * M_ + m] += pm.x * in[m].x + pm.y * in[m].y
                                     + pm.z * in[m].z + pm.w * in[m].w;
        }
    }

    // wave64 shuffle reduction (result lands on lane 0 of each wave)
#pragma unroll
    for (int off = 32; off > 0; off >>= 1) {
#pragma unroll
        for (int i = 0; i < NV; ++i)
            val[i] += __shfl_down(val[i], off, 64);
    }

    __shared__ float smem[TPB / 64][NV];
    const int lane = threadIdx.x & 63;
    const int wave = threadIdx.x >> 6;
    if (lane == 0) {
#pragma unroll
        for (int i = 0; i < NV; ++i) smem[wave][i] = val[i];
    }
    __syncthreads();

    if (threadIdx.x < NV) {
        const float s = smem[0][threadIdx.x] + smem[1][threadIdx.x]
                      + smem[2][threadIdx.x] + smem[3][threadIdx.x];
        partial_ws[((size_t)b * CHUNKS + c) * NV + threadIdx.x] = s;
    }
}

// One wave: lane b owns image b; sum its chunk-partials, form ratios,
// reduce the 12 ratios over b, write the scalar.
__global__ __launch_bounds__(64) void finalize_kernel(
    const float* __restrict__ partial_ws,  // [B,CHUNKS,NV]
    const float* __restrict__ mu_data,     // [K,M]
    float* __restrict__ out)               // [1]
{
    const int b = threadIdx.x;  // 0..63 == B_
    float acc[NV];
#pragma unroll
    for (int i = 0; i < NV; ++i) acc[i] = 0.0f;
    for (int c = 0; c < CHUNKS; ++c) {
        const float* p = partial_ws + ((size_t)b * CHUNKS + c) * NV;
#pragma unroll
        for (int i = 0; i < NV; ++i) acc[i] += p[i];
    }

    float r[K_ * M_];
#pragma unroll
    for (int k = 0; k < K_; ++k) {
        const float inv = 1.0f / (acc[k] + 1e-10f);
#pragma unroll
        for (int m = 0; m < M_; ++m)
            r[k * M_ + m] = acc[4 + k * M_ + m] * inv;
    }
#pragma unroll
    for (int off = 32; off > 0; off >>= 1) {
#pragma unroll
        for (int i = 0; i < K_ * M_; ++i)
            r[i] += __shfl_down(r[i], off, 64);
    }
    if (b == 0) {
        float s = 0.0f;
#pragma unroll
        for (int i = 0; i < K_ * M_; ++i) {
            const float d = mu_data[i] - r[i] * (1.0f / (float)B_);
            s += d * d;
        }
        out[0] = s;
    }
}

extern "C" void kernel_launch(void* const* d_in, const int* in_sizes, int n_in,
                              void* d_out, int out_size, void* d_ws, size_t ws_size,
                              hipStream_t stream) {
    const float* pred    = (const float*)d_in[0];  // [64,4,256,256] f32
    const float* inp     = (const float*)d_in[1];  // [64,3,256,256] f32
    const int*   heart   = (const int*)d_in[2];    // [64,1,256,256] i32
    const float* mu_data = (const float*)d_in[3];  // [4,3] f32
    float* out = (float*)d_out;

    float* partial_ws = (float*)d_ws;  // [B][CHUNKS][NV] — fully written each call

    dim3 grid(CHUNKS, B_);
    partial_kernel<<<grid, TPB, 0, stream>>>(pred, inp, heart, partial_ws);
    finalize_kernel<<<1, 64, 0, stream>>>(partial_ws, mu_data, out);
}

// Round 4
// 153.982 us; speedup vs baseline: 1.0970x; 1.0093x over previous
//
#include <hip/hip_runtime.h>

// Problem constants (fixed by reference setup_inputs)
#define B_      64
#define K_      4
#define M_      3
#define NPIX    65536      // X*Y = 256*256
#define CHUNKS  32         // blocks per image
#define TPB     256        // threads per block
#define ITERS   2          // float4 sub-iterations per thread (8 consecutive px)
#define NV      16         // 4 den + 12 num partials per thread

// Block (c, b) handles pixels [c*2048, (c+1)*2048) of image b.
// Two-phase body: ALL 16 vector loads issue first into register arrays
// (sched_barrier keeps them clustered), then the compute consumes them.
// R3 showed the compiler otherwise recycles registers into ~3-load batches
// (VGPR_Count=52) and exposes full memory latency every round.
// NOTE: no min-waves __launch_bounds__ cap — R2 showed capping at 64 VGPRs
// spills the batched loads to scratch (+26 MB WRITE_SIZE, +16 us).
__global__ __launch_bounds__(TPB) void partial_kernel(
    const float* __restrict__ pred,    // [B,K,NPIX]
    const float* __restrict__ inp,     // [B,M,NPIX]
    const int*   __restrict__ heart,   // [B,NPIX]
    float* __restrict__ partial_ws)    // [B,CHUNKS,NV]
{
    const int c = blockIdx.x;          // chunk 0..CHUNKS-1
    const int b = blockIdx.y;          // image 0..63
    const int base = c * (NPIX / CHUNKS) + (int)threadIdx.x * (4 * ITERS);

    // ---- phase 1: issue every load ----
    int4   h[ITERS];
    float4 in[ITERS][M_];
    float4 p[ITERS][K_];
#pragma unroll
    for (int it = 0; it < ITERS; ++it) {
        const int pix = base + it * 4;
        h[it] = *reinterpret_cast<const int4*>(heart + (size_t)b * NPIX + pix);
#pragma unroll
        for (int m = 0; m < M_; ++m)
            in[it][m] = *reinterpret_cast<const float4*>(inp + ((size_t)b * M_ + m) * NPIX + pix);
#pragma unroll
        for (int k = 0; k < K_; ++k)
            p[it][k] = *reinterpret_cast<const float4*>(pred + ((size_t)b * K_ + k) * NPIX + pix);
    }
    // Keep the 16 loads clustered above the compute (no cross-scheduling).
    __builtin_amdgcn_sched_barrier(0);

    // ---- phase 2: compute ----
    float val[NV];
#pragma unroll
    for (int i = 0; i < NV; ++i) val[i] = 0.0f;

#pragma unroll
    for (int it = 0; it < ITERS; ++it) {
        float4 mask;
        mask.x = (h[it].x == 1) ? 1.0f : 0.0f;
        mask.y = (h[it].y == 1) ? 1.0f : 0.0f;
        mask.z = (h[it].z == 1) ? 1.0f : 0.0f;
        mask.w = (h[it].w == 1) ? 1.0f : 0.0f;

#pragma unroll
        for (int k = 0; k < K_; ++k) {
            float4 pm;
            pm.x = p[it][k].x * mask.x; pm.y = p[it][k].y * mask.y;
            pm.z = p[it][k].z * mask.z; pm.w = p[it][k].w * mask.w;
            val[k] += (pm.x + pm.y) + (pm.z + pm.w);
#pragma unroll
            for (int m = 0; m < M_; ++m)
                val[4 + k * M_ + m] += pm.x * in[it][m].x + pm.y * in[it][m].y
                                     + pm.z * in[it][m].z + pm.w * in[it][m].w;
        }
    }

    // wave64 shuffle reduction (result lands on lane 0 of each wave)
#pragma unroll
    for (int off = 32; off > 0; off >>= 1) {
#pragma unroll
        for (int i = 0; i < NV; ++i)
            val[i] += __shfl_down(val[i], off, 64);
    }

    __shared__ float smem[TPB / 64][NV];
    const int lane = threadIdx.x & 63;
    const int wave = threadIdx.x >> 6;
    if (lane == 0) {
#pragma unroll
        for (int i = 0; i < NV; ++i) smem[wave][i] = val[i];
    }
    __syncthreads();

    if (threadIdx.x < NV) {
        const float s = smem[0][threadIdx.x] + smem[1][threadIdx.x]
                      + smem[2][threadIdx.x] + smem[3][threadIdx.x];
        partial_ws[((size_t)b * CHUNKS + c) * NV + threadIdx.x] = s;
    }
}

// One wave: lane b owns image b; sum its chunk-partials, form ratios,
// reduce the 12 ratios over b, write the scalar.
__global__ __launch_bounds__(64) void finalize_kernel(
    const float* __restrict__ partial_ws,  // [B,CHUNKS,NV]
    const float* __restrict__ mu_data,     // [K,M]
    float* __restrict__ out)               // [1]
{
    const int b = threadIdx.x;  // 0..63 == B_
    float acc[NV];
#pragma unroll
    for (int i = 0; i < NV; ++i) acc[i] = 0.0f;
    for (int c = 0; c < CHUNKS; ++c) {
        const float* p = partial_ws + ((size_t)b * CHUNKS + c) * NV;
#pragma unroll
        for (int i = 0; i < NV; ++i) acc[i] += p[i];
    }

    float r[K_ * M_];
#pragma unroll
    for (int k = 0; k < K_; ++k) {
        const float inv = 1.0f / (acc[k] + 1e-10f);
#pragma unroll
        for (int m = 0; m < M_; ++m)
            r[k * M_ + m] = acc[4 + k * M_ + m] * inv;
    }
#pragma unroll
    for (int off = 32; off > 0; off >>= 1) {
#pragma unroll
        for (int i = 0; i < K_ * M_; ++i)
            r[i] += __shfl_down(r[i], off, 64);
    }
    if (b == 0) {
        float s = 0.0f;
#pragma unroll
        for (int i = 0; i < K_ * M_; ++i) {
            const float d = mu_data[i] - r[i] * (1.0f / (float)B_);
            s += d * d;
        }
        out[0] = s;
    }
}

extern "C" void kernel_launch(void* const* d_in, const int* in_sizes, int n_in,
                              void* d_out, int out_size, void* d_ws, size_t ws_size,
                              hipStream_t stream) {
    const float* pred    = (const float*)d_in[0];  // [64,4,256,256] f32
    const float* inp     = (const float*)d_in[1];  // [64,3,256,256] f32
    const int*   heart   = (const int*)d_in[2];    // [64,1,256,256] i32
    const float* mu_data = (const float*)d_in[3];  // [4,3] f32
    float* out = (float*)d_out;

    float* partial_ws = (float*)d_ws;  // [B][CHUNKS][NV] — fully written each call

    dim3 grid(CHUNKS, B_);
    partial_kernel<<<grid, TPB, 0, stream>>>(pred, inp, heart, partial_ws);
    finalize_kernel<<<1, 64, 0, stream>>>(partial_ws, mu_data, out);
}

// Round 5
// 153.403 us; speedup vs baseline: 1.1012x; 1.0038x over previous
//
#include <hip/hip_runtime.h>

// Problem constants (fixed by reference setup_inputs)
#define B_      64
#define K_      4
#define M_      3
#define NPIX    65536      // X*Y = 256*256
#define CHUNKS  8          // blocks per image -> grid 512 = 2 blocks/CU
#define TPB     256        // threads per block
#define IT      8          // float4 iterations per thread (32 px/thread)
#define SPAN    (NPIX / CHUNKS)   // 8192 px per block
#define STRIDE  (TPB * 4)         // 1024 px per block-iteration
#define NV      16         // 4 den + 12 num partials per thread

struct LoadBatch {
    int4   h;
    float4 in[M_];
    float4 p[K_];
};

__device__ __forceinline__ void issue_loads(
    LoadBatch& L,
    const float* __restrict__ pred_b,   // pred + b*K*NPIX
    const float* __restrict__ inp_b,    // inp  + b*M*NPIX
    const int*   __restrict__ heart_b,  // heart + b*NPIX
    int pix)
{
    L.h = *reinterpret_cast<const int4*>(heart_b + pix);
#pragma unroll
    for (int m = 0; m < M_; ++m)
        L.in[m] = *reinterpret_cast<const float4*>(inp_b + (size_t)m * NPIX + pix);
#pragma unroll
    for (int k = 0; k < K_; ++k)
        L.p[k] = *reinterpret_cast<const float4*>(pred_b + (size_t)k * NPIX + pix);
}

__device__ __forceinline__ void consume(const LoadBatch& L, float* val)
{
    float4 mask;
    mask.x = (L.h.x == 1) ? 1.0f : 0.0f;
    mask.y = (L.h.y == 1) ? 1.0f : 0.0f;
    mask.z = (L.h.z == 1) ? 1.0f : 0.0f;
    mask.w = (L.h.w == 1) ? 1.0f : 0.0f;
#pragma unroll
    for (int k = 0; k < K_; ++k) {
        float4 pm;
        pm.x = L.p[k].x * mask.x; pm.y = L.p[k].y * mask.y;
        pm.z = L.p[k].z * mask.z; pm.w = L.p[k].w * mask.w;
        val[k] += (pm.x + pm.y) + (pm.z + pm.w);
#pragma unroll
        for (int m = 0; m < M_; ++m)
            val[4 + k * M_ + m] += pm.x * L.in[m].x + pm.y * L.in[m].y
                                 + pm.z * L.in[m].z + pm.w * L.in[m].w;
    }
}

// Block (c, b) handles pixels [c*8192, (c+1)*8192) of image b via 8
// iterations with an explicit 2-stage load/compute pipeline. Amortizes the
// wave reduction tail 8x and keeps each wave in load-steady-state
// (in-order vmcnt return: consuming batch A waits only while batch B is
// in flight). R2's spill trap avoided: only 2 batches (~64 payload VGPRs)
// live at once, no min-waves cap.
__global__ __launch_bounds__(TPB) void partial_kernel(
    const float* __restrict__ pred,    // [B,K,NPIX]
    const float* __restrict__ inp,     // [B,M,NPIX]
    const int*   __restrict__ heart,   // [B,NPIX]
    float* __restrict__ partial_ws)    // [B,CHUNKS,NV]
{
    const int c = blockIdx.x;          // chunk 0..CHUNKS-1
    const int b = blockIdx.y;          // image 0..63
    const int base = c * SPAN + (int)threadIdx.x * 4;

    const float* pred_b  = pred  + (size_t)b * K_ * NPIX;
    const float* inp_b   = inp   + (size_t)b * M_ * NPIX;
    const int*   heart_b = heart + (size_t)b * NPIX;

    float val[NV];
#pragma unroll
    for (int i = 0; i < NV; ++i) val[i] = 0.0f;

    LoadBatch A, Bb;
    issue_loads(A, pred_b, inp_b, heart_b, base);
#pragma unroll
    for (int j = 0; j < IT; j += 2) {
        if (j + 1 < IT) issue_loads(Bb, pred_b, inp_b, heart_b, base + (j + 1) * STRIDE);
        consume(A, val);
        if (j + 2 < IT) issue_loads(A, pred_b, inp_b, heart_b, base + (j + 2) * STRIDE);
        consume(Bb, val);
    }

    // wave64 shuffle reduction (result lands on lane 0 of each wave)
#pragma unroll
    for (int off = 32; off > 0; off >>= 1) {
#pragma unroll
        for (int i = 0; i < NV; ++i)
            val[i] += __shfl_down(val[i], off, 64);
    }

    __shared__ float smem[TPB / 64][NV];
    const int lane = threadIdx.x & 63;
    const int wave = threadIdx.x >> 6;
    if (lane == 0) {
#pragma unroll
        for (int i = 0; i < NV; ++i) smem[wave][i] = val[i];
    }
    __syncthreads();

    if (threadIdx.x < NV) {
        const float s = smem[0][threadIdx.x] + smem[1][threadIdx.x]
                      + smem[2][threadIdx.x] + smem[3][threadIdx.x];
        partial_ws[((size_t)b * CHUNKS + c) * NV + threadIdx.x] = s;
    }
}

// One wave: lane b owns image b; sum its chunk-partials, form ratios,
// reduce the 12 ratios over b, write the scalar.
__global__ __launch_bounds__(64) void finalize_kernel(
    const float* __restrict__ partial_ws,  // [B,CHUNKS,NV]
    const float* __restrict__ mu_data,     // [K,M]
    float* __restrict__ out)               // [1]
{
    const int b = threadIdx.x;  // 0..63 == B_
    float acc[NV];
#pragma unroll
    for (int i = 0; i < NV; ++i) acc[i] = 0.0f;
    for (int c = 0; c < CHUNKS; ++c) {
        const float* p = partial_ws + ((size_t)b * CHUNKS + c) * NV;
#pragma unroll
        for (int i = 0; i < NV; ++i) acc[i] += p[i];
    }

    float r[K_ * M_];
#pragma unroll
    for (int k = 0; k < K_; ++k) {
        const float inv = 1.0f / (acc[k] + 1e-10f);
#pragma unroll
        for (int m = 0; m < M_; ++m)
            r[k * M_ + m] = acc[4 + k * M_ + m] * inv;
    }
#pragma unroll
    for (int off = 32; off > 0; off >>= 1) {
#pragma unroll
        for (int i = 0; i < K_ * M_; ++i)
            r[i] += __shfl_down(r[i], off, 64);
    }
    if (b == 0) {
        float s = 0.0f;
#pragma unroll
        for (int i = 0; i < K_ * M_; ++i) {
            const float d = mu_data[i] - r[i] * (1.0f / (float)B_);
            s += d * d;
        }
        out[0] = s;
    }
}

extern "C" void kernel_launch(void* const* d_in, const int* in_sizes, int n_in,
                              void* d_out, int out_size, void* d_ws, size_t ws_size,
                              hipStream_t stream) {
    const float* pred    = (const float*)d_in[0];  // [64,4,256,256] f32
    const float* inp     = (const float*)d_in[1];  // [64,3,256,256] f32
    const int*   heart   = (const int*)d_in[2];    // [64,1,256,256] i32
    const float* mu_data = (const float*)d_in[3];  // [4,3] f32
    float* out = (float*)d_out;

    float* partial_ws = (float*)d_ws;  // [B][CHUNKS][NV] — fully written each call

    dim3 grid(CHUNKS, B_);
    partial_kernel<<<grid, TPB, 0, stream>>>(pred, inp, heart, partial_ws);
    finalize_kernel<<<1, 64, 0, stream>>>(partial_ws, mu_data, out);
}